// Round 1
// baseline (58.367 us; speedup 1.0000x reference)
//
#include <hip/hip_runtime.h>
#include <math.h>

// DecodeBox: input [B=4, A*10=30, D=64, H=64, W=64] f32
// output [B, A*D*H*W, 10] f32
// attrs out: bx, by, bz, bl, conf, cls0..cls4
//   bx = (sigmoid(p0) + w) * 4 ; by = (sigmoid(p1) + h) * 4 ; bz = (sigmoid(p2) + d) * 4
//   bl = exp(p3) * anchor_w[a]   (anchor_w/stride * stride cancels -> {10,16,33})
//   conf/cls = sigmoid

constexpr int A_NUM  = 3;
constexpr int ATTRS  = 10;
constexpr int DD = 64, HH = 64, WW = 64;
constexpr int SPATIAL = DD * HH * WW;   // 262144

__device__ __forceinline__ float sigmoidf_fast(float x) {
    return 1.0f / (1.0f + __expf(-x));
}

__global__ __launch_bounds__(256) void decode_box_kernel(const float* __restrict__ in,
                                                         float* __restrict__ out,
                                                         int total4) {
    int t = blockIdx.x * 256 + threadIdx.x;
    if (t >= total4) return;

    int idx = t << 2;                 // linear (b*A + a)*SPATIAL + s, s multiple of 4
    int s   = idx & (SPATIAL - 1);    // spatial index within (d,h,w)
    int ba  = idx >> 18;              // b*3 + a   (SPATIAL = 2^18)
    int a   = ba % A_NUM;
    int w   = s & (WW - 1);
    int h   = (s >> 6) & (HH - 1);
    int d   = s >> 12;

    const float* base = in + (size_t)ba * ATTRS * SPATIAL + s;

    float p[ATTRS][4];
#pragma unroll
    for (int k = 0; k < ATTRS; ++k) {
        float4 v = *reinterpret_cast<const float4*>(base + (size_t)k * SPATIAL);
        p[k][0] = v.x; p[k][1] = v.y; p[k][2] = v.z; p[k][3] = v.w;
    }

    float aw = (a == 0) ? 10.0f : (a == 1 ? 16.0f : 33.0f);
    float fh = (float)h * 4.0f;
    float fd = (float)d * 4.0f;

    float o[4 * ATTRS];
#pragma unroll
    for (int j = 0; j < 4; ++j) {
        float* oj = o + j * ATTRS;
        oj[0] = sigmoidf_fast(p[0][j]) * 4.0f + (float)(w + j) * 4.0f;
        oj[1] = sigmoidf_fast(p[1][j]) * 4.0f + fh;
        oj[2] = sigmoidf_fast(p[2][j]) * 4.0f + fd;
        oj[3] = __expf(p[3][j]) * aw;
        oj[4] = sigmoidf_fast(p[4][j]);
#pragma unroll
        for (int c = 0; c < 5; ++c)
            oj[5 + c] = sigmoidf_fast(p[5 + c][j]);
    }

    float4* o4 = reinterpret_cast<float4*>(out + (size_t)idx * ATTRS);
#pragma unroll
    for (int i = 0; i < ATTRS; ++i)
        o4[i] = make_float4(o[4 * i], o[4 * i + 1], o[4 * i + 2], o[4 * i + 3]);
}

extern "C" void kernel_launch(void* const* d_in, const int* in_sizes, int n_in,
                              void* d_out, int out_size, void* d_ws, size_t ws_size,
                              hipStream_t stream) {
    const float* in = (const float*)d_in[0];
    float* out = (float*)d_out;

    int total  = in_sizes[0] / ATTRS;  // B*A*SPATIAL = 3,145,728 rows
    int total4 = total / 4;            // 786,432 threads
    int blocks = (total4 + 255) / 256; // 3072 blocks

    decode_box_kernel<<<blocks, 256, 0, stream>>>(in, out, total4);
}

// Round 2
// 42.325 us; speedup vs baseline: 1.3790x; 1.3790x over previous
//
#include <hip/hip_runtime.h>
#include <math.h>

// DecodeBox: input [B=4, A*10=30, D=64, H=64, W=64] f32
// output [B, A*D*H*W, 10] f32
// attrs out: bx, by, bz, bl, conf, cls0..cls4
//   bx = (sigmoid(p0) + w) * 4 ; by = (sigmoid(p1) + h) * 4 ; bz = (sigmoid(p2) + d) * 4
//   bl = exp(p3) * anchor_w[a]   (anchor_w/stride * stride cancels -> {10,16,33})
//   conf/cls = sigmoid
//
// Store path is LDS-staged: each block computes 1024 rows (4/thread) into a
// 40 KB LDS tile in output layout, then streams the tile out as contiguous
// float4 stores (1 KB per wave store instruction vs 64 scattered 16B segments
// in the unstaged version).

constexpr int A_NUM  = 3;
constexpr int ATTRS  = 10;
constexpr int DD = 64, HH = 64, WW = 64;
constexpr int SPATIAL = DD * HH * WW;   // 262144
constexpr int BLOCK = 256;
constexpr int ROWS_PER_THREAD = 4;
constexpr int CHUNK_ROWS = BLOCK * ROWS_PER_THREAD;          // 1024
constexpr int CHUNK_VEC4 = CHUNK_ROWS * ATTRS / 4;           // 2560 float4 = 40 KB

__device__ __forceinline__ float sigmoidf_fast(float x) {
    return 1.0f / (1.0f + __expf(-x));
}

__global__ __launch_bounds__(256) void decode_box_kernel(const float* __restrict__ in,
                                                         float* __restrict__ out) {
    __shared__ float4 tile[CHUNK_VEC4];

    int tid = threadIdx.x;
    int t   = blockIdx.x * BLOCK + tid;

    int idx = t << 2;                 // linear row = (b*A + a)*SPATIAL + s, s multiple of 4
    int s   = idx & (SPATIAL - 1);    // spatial index within (d,h,w)
    int ba  = idx >> 18;              // b*3 + a   (SPATIAL = 2^18)
    int a   = ba % A_NUM;
    int w   = s & (WW - 1);
    int h   = (s >> 6) & (HH - 1);
    int d   = s >> 12;

    const float* base = in + (size_t)ba * ATTRS * SPATIAL + s;

    float p[ATTRS][4];
#pragma unroll
    for (int k = 0; k < ATTRS; ++k) {
        float4 v = *reinterpret_cast<const float4*>(base + (size_t)k * SPATIAL);
        p[k][0] = v.x; p[k][1] = v.y; p[k][2] = v.z; p[k][3] = v.w;
    }

    float aw = (a == 0) ? 10.0f : (a == 1 ? 16.0f : 33.0f);
    float fh = (float)h * 4.0f;
    float fd = (float)d * 4.0f;

    float o[4 * ATTRS];
#pragma unroll
    for (int j = 0; j < 4; ++j) {
        float* oj = o + j * ATTRS;
        oj[0] = sigmoidf_fast(p[0][j]) * 4.0f + (float)(w + j) * 4.0f;
        oj[1] = sigmoidf_fast(p[1][j]) * 4.0f + fh;
        oj[2] = sigmoidf_fast(p[2][j]) * 4.0f + fd;
        oj[3] = __expf(p[3][j]) * aw;
        oj[4] = sigmoidf_fast(p[4][j]);
#pragma unroll
        for (int c = 0; c < 5; ++c)
            oj[5 + c] = sigmoidf_fast(p[5 + c][j]);
    }

    // Stage this thread's 10 float4s (40 contiguous output floats) into LDS.
#pragma unroll
    for (int i = 0; i < ATTRS; ++i)
        tile[tid * ATTRS + i] = make_float4(o[4 * i], o[4 * i + 1], o[4 * i + 2], o[4 * i + 3]);

    __syncthreads();

    // Stream the 40 KB tile to global, fully coalesced: each wave store
    // instruction covers 1024 contiguous bytes.
    float4* o4 = reinterpret_cast<float4*>(out) + (size_t)blockIdx.x * CHUNK_VEC4;
#pragma unroll
    for (int i = 0; i < ATTRS; ++i)
        o4[i * BLOCK + tid] = tile[i * BLOCK + tid];
}

extern "C" void kernel_launch(void* const* d_in, const int* in_sizes, int n_in,
                              void* d_out, int out_size, void* d_ws, size_t ws_size,
                              hipStream_t stream) {
    const float* in = (const float*)d_in[0];
    float* out = (float*)d_out;

    int total  = in_sizes[0] / ATTRS;          // B*A*SPATIAL = 3,145,728 rows
    int blocks = total / CHUNK_ROWS;           // 3072 blocks

    decode_box_kernel<<<blocks, BLOCK, 0, stream>>>(in, out);
}

// Round 3
// 41.506 us; speedup vs baseline: 1.4062x; 1.0197x over previous
//
#include <hip/hip_runtime.h>
#include <math.h>

// DecodeBox: input [B=4, A*10=30, D=64, H=64, W=64] f32
// output [B, A*D*H*W, 10] f32
// attrs out: bx, by, bz, bl, conf, cls0..cls4
//   bx = (sigmoid(p0) + w) * 4 ; by = (sigmoid(p1) + h) * 4 ; bz = (sigmoid(p2) + d) * 4
//   bl = exp(p3) * anchor_w[a]   (anchor_w/stride * stride cancels -> {10,16,33})
//   conf/cls = sigmoid
//
// Store path is LDS-staged in TWO half-tile passes (20 KB LDS instead of 40 KB)
// so 8 blocks/CU fit (160 KB LDS/CU) -> full occupancy for latency hiding.
// Loads stay float4-coalesced; flush stores are fully contiguous float4.

constexpr int A_NUM  = 3;
constexpr int ATTRS  = 10;
constexpr int DD = 64, HH = 64, WW = 64;
constexpr int SPATIAL = DD * HH * WW;   // 262144
constexpr int BLOCK = 256;
constexpr int ROWS_PER_THREAD = 4;
constexpr int CHUNK_ROWS = BLOCK * ROWS_PER_THREAD;          // 1024 rows/block
constexpr int CHUNK_VEC4 = CHUNK_ROWS * ATTRS / 4;           // 2560 float4 = 40 KB out/block
constexpr int HALF_VEC4  = CHUNK_VEC4 / 2;                   // 1280 float4 = 20 KB LDS

__device__ __forceinline__ float sigmoidf_fast(float x) {
    return 1.0f / (1.0f + __expf(-x));
}

__global__ __launch_bounds__(256) void decode_box_kernel(const float* __restrict__ in,
                                                         float* __restrict__ out) {
    __shared__ float4 tile[HALF_VEC4];

    int tid = threadIdx.x;
    int t   = blockIdx.x * BLOCK + tid;

    int idx = t << 2;                 // linear row = (b*A + a)*SPATIAL + s, s multiple of 4
    int s   = idx & (SPATIAL - 1);    // spatial index within (d,h,w)
    int ba  = idx >> 18;              // b*3 + a   (SPATIAL = 2^18)
    int a   = ba % A_NUM;
    int w   = s & (WW - 1);
    int h   = (s >> 6) & (HH - 1);
    int d   = s >> 12;

    const float* base = in + (size_t)ba * ATTRS * SPATIAL + s;

    float p[ATTRS][4];
#pragma unroll
    for (int k = 0; k < ATTRS; ++k) {
        float4 v = *reinterpret_cast<const float4*>(base + (size_t)k * SPATIAL);
        p[k][0] = v.x; p[k][1] = v.y; p[k][2] = v.z; p[k][3] = v.w;
    }

    float aw = (a == 0) ? 10.0f : (a == 1 ? 16.0f : 33.0f);
    float fh = (float)h * 4.0f;
    float fd = (float)d * 4.0f;

    float o[4 * ATTRS];
#pragma unroll
    for (int j = 0; j < 4; ++j) {
        float* oj = o + j * ATTRS;
        oj[0] = sigmoidf_fast(p[0][j]) * 4.0f + (float)(w + j) * 4.0f;
        oj[1] = sigmoidf_fast(p[1][j]) * 4.0f + fh;
        oj[2] = sigmoidf_fast(p[2][j]) * 4.0f + fd;
        oj[3] = __expf(p[3][j]) * aw;
        oj[4] = sigmoidf_fast(p[4][j]);
#pragma unroll
        for (int c = 0; c < 5; ++c)
            oj[5 + c] = sigmoidf_fast(p[5 + c][j]);
    }

    float4* o4 = reinterpret_cast<float4*>(out) + (size_t)blockIdx.x * CHUNK_VEC4;

    // ---- pass 0: rows 0..511 (threads 0..127 own them) ----
    if (tid < 128) {
#pragma unroll
        for (int i = 0; i < ATTRS; ++i)
            tile[tid * ATTRS + i] = make_float4(o[4 * i], o[4 * i + 1], o[4 * i + 2], o[4 * i + 3]);
    }
    __syncthreads();
#pragma unroll
    for (int i = 0; i < HALF_VEC4 / BLOCK; ++i)          // 5 float4 per thread
        o4[i * BLOCK + tid] = tile[i * BLOCK + tid];
    __syncthreads();

    // ---- pass 1: rows 512..1023 (threads 128..255 own them) ----
    if (tid >= 128) {
#pragma unroll
        for (int i = 0; i < ATTRS; ++i)
            tile[(tid - 128) * ATTRS + i] = make_float4(o[4 * i], o[4 * i + 1], o[4 * i + 2], o[4 * i + 3]);
    }
    __syncthreads();
#pragma unroll
    for (int i = 0; i < HALF_VEC4 / BLOCK; ++i)
        o4[HALF_VEC4 + i * BLOCK + tid] = tile[i * BLOCK + tid];
}

extern "C" void kernel_launch(void* const* d_in, const int* in_sizes, int n_in,
                              void* d_out, int out_size, void* d_ws, size_t ws_size,
                              hipStream_t stream) {
    const float* in = (const float*)d_in[0];
    float* out = (float*)d_out;

    int total  = in_sizes[0] / ATTRS;          // B*A*SPATIAL = 3,145,728 rows
    int blocks = total / CHUNK_ROWS;           // 3072 blocks

    decode_box_kernel<<<blocks, BLOCK, 0, stream>>>(in, out);
}